// Round 6
// baseline (401.661 us; speedup 1.0000x reference)
//
#include <hip/hip_runtime.h>
#include <hip/hip_bf16.h>

typedef __hip_bfloat16 bf16;

#define B_   8
#define C_   192
#define OC3  576
#define H_   128
#define W_   128
#define HW_  16384
#define HEADS_ 4
#define D_   48

typedef float f32x4 __attribute__((ext_vector_type(4)));
typedef __bf16 bf16x8 __attribute__((ext_vector_type(8)));
typedef __bf16 bf16x4 __attribute__((ext_vector_type(4)));

__device__ __forceinline__ float b2f(bf16 v) { return __bfloat162float(v); }

// packed 4-wide epilogue stores (p-contiguous)
__device__ __forceinline__ void stv4(bf16* p, const f32x4& v, float bi) {
    bf16x4 o;
#pragma unroll
    for (int r = 0; r < 4; ++r) o[r] = (__bf16)(v[r] + bi);
    *reinterpret_cast<bf16x4*>(p) = o;
}
__device__ __forceinline__ void stv4(float* p, const f32x4& v, float bi) {
    f32x4 o;
#pragma unroll
    for (int r = 0; r < 4; ++r) o[r] = v[r] + bi;
    *reinterpret_cast<f32x4*>(p) = o;
}

// async 16B global -> LDS (per-lane global addr; LDS dest = wave-uniform base + lane*16)
__device__ __forceinline__ void llds16(const void* g, void* l) {
    __builtin_amdgcn_global_load_lds(
        (const __attribute__((address_space(1))) unsigned int*)g,
        (__attribute__((address_space(3))) unsigned int*)l, 16, 0, 0);
}

// ---------------------------------------------------------------------------
// Convert qkv_w (576x192) fp32 -> bf16 (rows padded to 640; pad rows = finite
// poison, masked at GEMM store). grid 576 x 192 threads.
// ---------------------------------------------------------------------------
__global__ void cvt_w(const float* __restrict__ qkv_w, __bf16* __restrict__ Wq) {
    const int row = blockIdx.x, c = threadIdx.x;
    Wq[row * C_ + c] = (__bf16)qkv_w[row * C_ + c];
}

// ---------------------------------------------------------------------------
// Transpose-convert x[b][c][p] fp32 -> Xt[b][p][c] bf16.
// ---------------------------------------------------------------------------
__global__ void tx_cvt(const float* __restrict__ x, __bf16* __restrict__ Xt) {
    const int p0 = blockIdx.x * 128;
    const int b  = blockIdx.z;
    __shared__ __bf16 LT[128 * 196];

    for (int idx = threadIdx.x; idx < C_ * 128; idx += 256) {
        int c = idx >> 7, pp = idx & 127;
        LT[pp * 196 + c] = (__bf16)x[((size_t)b * C_ + c) * HW_ + p0 + pp];
    }
    __syncthreads();
    for (int idx = threadIdx.x; idx < 128 * 48; idx += 256) {
        int pp = idx / 48, c4 = idx % 48;
        *(uint2*)&Xt[((size_t)b * HW_ + p0 + pp) * C_ + c4 * 4] =
            *(const uint2*)&LT[pp * 196 + c4 * 4];
    }
}

// ---------------------------------------------------------------------------
// Transpose v-part of qkv2: vt[b][p][c] (c=0..191 => channel 384+c) bf16.
// ---------------------------------------------------------------------------
__global__ void vtx(const bf16* __restrict__ qkv2, __bf16* __restrict__ vt) {
    const int p0 = blockIdx.x * 128;
    const int b  = blockIdx.z;
    const bf16* vb = qkv2 + ((size_t)b * OC3 + 384) * HW_;
    __shared__ __bf16 LT[128 * 200];

    for (int idx = threadIdx.x; idx < C_ * 128; idx += 256) {
        int c = idx >> 7, pp = idx & 127;
        LT[pp * 200 + c] = *(const __bf16*)&vb[(size_t)c * HW_ + p0 + pp];
    }
    __syncthreads();
    for (int idx = threadIdx.x; idx < 128 * 48; idx += 256) {
        int pp = idx / 48, c4 = idx % 48;
        *(uint2*)&vt[((size_t)b * HW_ + p0 + pp) * C_ + c4 * 4] =
            *(const uint2*)&LT[pp * 200 + c4 * 4];
    }
}

// ---------------------------------------------------------------------------
// MFMA GEMM (BT form): Y[b][o][p] = sum_k A[o][k] * Xt[b][p][k] + bias[o]
// A rows padded to grid_y*128; a_bstride selects per-batch A (0 = shared).
//
// v5 (resubmit; round-5 bench was an infra failure, kernel never measured):
//     BM=128 x BN=256, 8 waves. Canonical 2-deep T3 pipeline (48 KB LDS ->
//     3 blocks/CU = 24 waves/CU): per iter {stage(next) ; ds_read+MFMA(cur) ;
//     vmcnt(0)+barrier}. One barrier per K-step. FETCH counters show the Xt
//     stream is L2/L3-resident (~200-300cy), so a single compute phase covers
//     the stage latency; the extra occupancy mixes epilogue stores with other
//     blocks' K-loops (HBM was idle during K-loop, bunched at epilogues).
//     T5 setprio(1) around the MFMA cluster (role diversity now exists).
//     Both-sides XOR swizzle retained (staging 64B-contiguous per row,
//     ds_read starting banks 2-way max = free). MFMA operands swapped
//     (X as A operand) -> acc regs run along p -> packed epilogue stores.
// ---------------------------------------------------------------------------
template<typename TOut, int KK>
__global__ __launch_bounds__(512, 4) void mfma_gemm(
        const __bf16* __restrict__ Wp, const __bf16* __restrict__ Xt,
        const float* __restrict__ bias, TOut* __restrict__ Y,
        const int O, const size_t a_bstride) {
    const int tid  = threadIdx.x;
    const int wid  = tid >> 6, lane = tid & 63;
    const int lm   = lane & 15, qd = lane >> 4;
    const int p0   = blockIdx.x * 256;
    const int o0   = blockIdx.y * 128;
    const int b    = blockIdx.z;
    const int wo0  = (wid >> 2) * 64;      // 2 o-rows of waves
    const int wn0  = (wid & 3) * 64;       // 4 p-cols of waves

    const __bf16* Wb = Wp + a_bstride * b + (size_t)o0 * KK;
    const __bf16* Xb = Xt + ((size_t)b * HW_ + p0) * KK;

    // [buf][row][slot][8] bf16 (lane-linear for global_load_lds); the 16B
    // chunk at (row,slot) holds global k8 = slot ^ ((row>>1)&3).
    __shared__ __bf16 As[2][4096];    // 128 rows x 32k  (8 KB/buf)
    __shared__ __bf16 Bs[2][8192];    // 256 rows x 32k  (16 KB/buf)

    f32x4 acc[4][4] = {};

    auto stage = [&](int buf, int t) {
        const int k0 = t * 32;
        {   // A: 128 rows x 4 chunks = 512 = 1/thread
            const int row = tid >> 2, cslot = tid & 3;
            const int k8  = cslot ^ ((row >> 1) & 3);
            llds16(Wb + (size_t)row * KK + k0 + k8 * 8,
                   &As[buf][(size_t)(wid * 64) * 8]);
        }
#pragma unroll
        for (int r = 0; r < 2; ++r) {   // B: 256 rows x 4 chunks = 1024 = 2/thread
            const int slot = r * 512 + tid;
            const int row  = slot >> 2, cslot = slot & 3;
            const int k8   = cslot ^ ((row >> 1) & 3);
            llds16(Xb + (size_t)row * KK + k0 + k8 * 8,
                   &Bs[buf][(size_t)(r * 512 + wid * 64) * 8]);
        }
    };

    constexpr int NT = KK >> 5;     // 6

    // prologue: tile 0 staged and landed
    stage(0, 0);
    asm volatile("s_waitcnt vmcnt(0)" ::: "memory");
    __builtin_amdgcn_s_barrier();
    __builtin_amdgcn_sched_barrier(0);

    const int csl = qd ^ ((lm >> 1) & 3);  // swizzled chunk slot for ds_read

#pragma unroll
    for (int t = 0; t < NT; ++t) {
        const int cur = t & 1;                       // static after unroll
        if (t + 1 < NT) stage(cur ^ 1, t + 1);       // issue next-tile loads

        bf16x8 af[4], bfr[4];
#pragma unroll
        for (int i = 0; i < 4; ++i)
            af[i] = *(const bf16x8*)&As[cur][((wo0 + i * 16 + lm) * 4 + csl) * 8];
#pragma unroll
        for (int j = 0; j < 4; ++j)
            bfr[j] = *(const bf16x8*)&Bs[cur][((wn0 + j * 16 + lm) * 4 + csl) * 8];

        __builtin_amdgcn_s_setprio(1);
#pragma unroll
        for (int i = 0; i < 4; ++i)
#pragma unroll
            for (int j = 0; j < 4; ++j)
                // swapped: X-frag is the A operand -> D reg index runs along p
                acc[i][j] = __builtin_amdgcn_mfma_f32_16x16x32_bf16(
                    bfr[j], af[i], acc[i][j], 0, 0, 0);
        __builtin_amdgcn_s_setprio(0);

        if (t + 1 < NT) {
            __builtin_amdgcn_sched_barrier(0);
            asm volatile("s_waitcnt vmcnt(0)" ::: "memory");  // next tile landed
            __builtin_amdgcn_s_barrier();
            __builtin_amdgcn_sched_barrier(0);
        }
    }

    // epilogue: acc[i][j][r] = Y[o0+wo0+i*16+lm][p0+wn0+j*16+qd*4+r]
    TOut* Yb = Y + (size_t)b * O * HW_;
#pragma unroll
    for (int i = 0; i < 4; ++i) {
        const int o = o0 + wo0 + i * 16 + lm;
        if (o < O) {
            const float bi = bias[o];
#pragma unroll
            for (int j = 0; j < 4; ++j) {
                const int p = p0 + wn0 + j * 16 + qd * 4;
                stv4(&Yb[(size_t)o * HW_ + p], acc[i][j], bi);
            }
        }
    }
}

// ---------------------------------------------------------------------------
// depthwise 3x3 + fused sum-of-squares (for q,k L2 norms).
// grid (ch=576, b=8), block 256. Whole 128x128 plane staged in LDS (32 KB).
// ---------------------------------------------------------------------------
__device__ __forceinline__ void dw_load_row(const __bf16* plane, int yy, int x0,
                                            float* r) {
    if (yy < 0 || yy > 127) {
#pragma unroll
        for (int i = 0; i < 10; ++i) r[i] = 0.f;
        return;
    }
    const __bf16* row = plane + yy * 128;
    bf16x8 v = *(const bf16x8*)(row + x0);
    r[0] = (x0 > 0) ? (float)row[x0 - 1] : 0.f;
#pragma unroll
    for (int i = 0; i < 8; ++i) r[1 + i] = (float)v[i];
    r[9] = (x0 + 8 < 128) ? (float)row[x0 + 8] : 0.f;
}

__global__ __launch_bounds__(256) void dwconv_fused(
        const bf16* __restrict__ in, const float* __restrict__ w9,
        const float* __restrict__ bias, bf16* __restrict__ out,
        float* __restrict__ sumsq) {
    const int ch = blockIdx.x;
    const int b  = blockIdx.y;
    const int tid = threadIdx.x;
    const char* ib = (const char*)(in + ((size_t)b * OC3 + ch) * HW_);

    __shared__ __bf16 plane[16384];
    __shared__ float red[256];

    {
        const int wid = tid >> 6, lane = tid & 63;
        char* lbase = (char*)plane + wid * 8192;
        const char* gbase = ib + wid * 8192;
#pragma unroll
        for (int i = 0; i < 8; ++i)
            llds16(gbase + i * 1024 + lane * 16, lbase + i * 1024);
    }

    float wv[9];
#pragma unroll
    for (int i = 0; i < 9; ++i) wv[i] = w9[ch * 9 + i];
    const float bi = bias[ch];

    __syncthreads();

    const int x0 = (tid & 15) * 8;
    const int y0 = (tid >> 4) * 8;
    bf16* ob = out + ((size_t)b * OC3 + ch) * HW_;

    float r0[10], r1[10], r2[10];
    dw_load_row(plane, y0 - 1, x0, r0);
    dw_load_row(plane, y0,     x0, r1);

    float ss = 0.f;
#pragma unroll
    for (int yi = 0; yi < 8; ++yi) {
        dw_load_row(plane, y0 + yi + 1, x0, r2);
        bf16x8 st;
#pragma unroll
        for (int xx = 0; xx < 8; ++xx) {
            float o = bi;
#pragma unroll
            for (int dx = 0; dx < 3; ++dx) {
                o += wv[0 + dx] * r0[xx + dx];
                o += wv[3 + dx] * r1[xx + dx];
                o += wv[6 + dx] * r2[xx + dx];
            }
            ss += o * o;
            st[xx] = (__bf16)o;
        }
        *(bf16x8*)(ob + (y0 + yi) * 128 + x0) = st;
#pragma unroll
        for (int i = 0; i < 10; ++i) { r0[i] = r1[i]; r1[i] = r2[i]; }
    }

    red[tid] = ss;
    __syncthreads();
    for (int stx = 128; stx > 0; stx >>= 1) {
        if (tid < stx) red[tid] += red[tid + stx];
        __syncthreads();
    }
    if (tid == 0) sumsq[b * OC3 + ch] = red[0];
}

// ---------------------------------------------------------------------------
// MFMA QK^T partials: S_part[slice][i][j] = sum_{n in 512-slice} q[i,n]*k[j,n]
// grid (32, HEADS, B), 256 thr. LDS: q/k chunks 48x128, rows padded to 136
// (row stride 17*16B => 2-way max bank aliasing on ds_read_b128). 4 waves
// split each 128-chunk into K=32 pieces; fp32 cross-wave reduce in LDS.
// ---------------------------------------------------------------------------
__global__ __launch_bounds__(256) void qk_mfma(const bf16* __restrict__ qkv2,
                                               float* __restrict__ Spart) {
    const int slice = blockIdx.x, h = blockIdx.y, b = blockIdx.z;
    const __bf16* qb = (const __bf16*)(qkv2 + ((size_t)b * OC3 + h * D_) * HW_);
    const __bf16* kb = (const __bf16*)(qkv2 + ((size_t)b * OC3 + 192 + h * D_) * HW_);

    __shared__ char smem[36864];                 // max(staging 26112, reduce 36864)
    __bf16* qs = (__bf16*)smem;                  // 48 x 136
    __bf16* ks = (__bf16*)(smem + 13056);        // 48 x 136
    float*  red = (float*)smem;                  // 4 x 2304

    const int tid = threadIdx.x, wid = tid >> 6, lane = tid & 63;
    const int lm = lane & 15, qd = lane >> 4;
    const int kw0 = wid * 32;

    f32x4 acc[3][3] = {};

    for (int sub = 0; sub < 4; ++sub) {
        const int n0 = slice * 512 + sub * 128;
        __syncthreads();
        for (int t = tid; t < 768; t += 256) {
            int r = t >> 4, c8 = t & 15;
            *(bf16x8*)&qs[r * 136 + c8 * 8] =
                *(const bf16x8*)(qb + (size_t)r * HW_ + n0 + c8 * 8);
            *(bf16x8*)&ks[r * 136 + c8 * 8] =
                *(const bf16x8*)(kb + (size_t)r * HW_ + n0 + c8 * 8);
        }
        __syncthreads();

        bf16x8 af[3], bfr[3];
#pragma unroll
        for (int i = 0; i < 3; ++i)
            af[i] = *(const bf16x8*)&qs[(i * 16 + lm) * 136 + kw0 + qd * 8];
#pragma unroll
        for (int j = 0; j < 3; ++j)
            bfr[j] = *(const bf16x8*)&ks[(j * 16 + lm) * 136 + kw0 + qd * 8];
#pragma unroll
        for (int i = 0; i < 3; ++i)
#pragma unroll
            for (int j = 0; j < 3; ++j)
                acc[i][j] = __builtin_amdgcn_mfma_f32_16x16x32_bf16(
                    af[i], bfr[j], acc[i][j], 0, 0, 0);
    }

    __syncthreads();
    float* wb = red + wid * 2304;
#pragma unroll
    for (int i = 0; i < 3; ++i)
#pragma unroll
        for (int j = 0; j < 3; ++j)
#pragma unroll
            for (int r = 0; r < 4; ++r)
                wb[(i * 16 + qd * 4 + r) * 48 + j * 16 + lm] = acc[i][j][r];
    __syncthreads();

    float* outp = Spart + ((size_t)((b * HEADS_ + h) * 32 + slice)) * 2304;
    for (int t = tid; t < 2304; t += 256)
        outp[t] = red[t] + red[2304 + t] + red[4608 + t] + red[6912 + t];
}

// ---------------------------------------------------------------------------
// Parallel 32-slice reduction: Sred[bh][t] = sum_sl Spart[bh][sl][t].
// grid (9, 32bh) x 256 thr = one thread per output element; coalesced loads.
// ---------------------------------------------------------------------------
__global__ void sreduce(const float* __restrict__ Spart, float* __restrict__ Sred) {
    const int bh = blockIdx.y;
    const int t  = blockIdx.x * 256 + threadIdx.x;   // 9*256 = 2304 exactly
    const float* Sp = Spart + (size_t)bh * 32 * 2304;
    float v = 0.f;
#pragma unroll
    for (int sl = 0; sl < 32; ++sl) v += Sp[sl * 2304 + t];
    Sred[(size_t)bh * 2304 + t] = v;
}

// ---------------------------------------------------------------------------
// apply norms (from fused sumsq) + temperature, softmax over pre-reduced S.
// ---------------------------------------------------------------------------
__global__ void softmax48(const float* __restrict__ Sred, const float* __restrict__ sumsq,
                          const float* __restrict__ temp, float* __restrict__ A) {
    const int h = blockIdx.x, b = blockIdx.y;
    const int i = threadIdx.x;
    if (i >= 48) return;
    const float* sq = sumsq + b * OC3 + h * D_;
    const float* sk = sumsq + b * OC3 + 192 + h * D_;
    const float t = temp[h];
    const float* Sp = Sred + (size_t)(b * HEADS_ + h) * 2304;

    const float rqi = 1.0f / fmaxf(sqrtf(sq[i]), 1e-12f);

    float s[48];
#pragma unroll
    for (int j = 0; j < 48; ++j)
        s[j] = Sp[i * 48 + j] * rqi * (1.0f / fmaxf(sqrtf(sk[j]), 1e-12f)) * t;
    float m = -1e30f;
#pragma unroll
    for (int j = 0; j < 48; ++j) m = fmaxf(m, s[j]);
    float sum = 0.f;
#pragma unroll
    for (int j = 0; j < 48; ++j) { s[j] = expf(s[j] - m); sum += s[j]; }
    float inv = 1.0f / sum;
    float* Ao = A + ((size_t)(b * HEADS_ + h) * 48 + i) * 48;
#pragma unroll
    for (int j = 0; j < 48; ++j) Ao[j] = s[j] * inv;
}

// ---------------------------------------------------------------------------
// Wf[b][o][c'] = sum_i proj_w[o][h*48+i] * A[b,h][i][j]   (c' = h*48+j)
// ---------------------------------------------------------------------------
__global__ void wfuse(const float* __restrict__ proj_w, const float* __restrict__ A,
                      __bf16* __restrict__ Wf) {
    const int o = blockIdx.x, b = blockIdx.y;
    const int cp = threadIdx.x;
    const int h = cp / 48, j = cp % 48;
    const float* wrow = proj_w + o * C_ + h * D_;
    const float* Ah = A + (size_t)(b * HEADS_ + h) * 2304;
    float s = 0.f;
#pragma unroll
    for (int i = 0; i < 48; ++i) s += wrow[i] * Ah[i * 48 + j];
    Wf[((size_t)b * 256 + o) * C_ + cp] = (__bf16)s;
}

// ---------------------------------------------------------------------------
extern "C" void kernel_launch(void* const* d_in, const int* in_sizes, int n_in,
                              void* d_out, int out_size, void* d_ws, size_t ws_size,
                              hipStream_t stream) {
    const float* x      = (const float*)d_in[0];
    const float* qkv_w  = (const float*)d_in[1];
    const float* qkv_b  = (const float*)d_in[2];
    const float* dw_w   = (const float*)d_in[3];
    const float* dw_b   = (const float*)d_in[4];
    const float* temp   = (const float*)d_in[5];
    const float* proj_w = (const float*)d_in[6];
    const float* proj_b = (const float*)d_in[7];
    float* out = (float*)d_out;

    char* ws = (char*)d_ws;
    const size_t XT_BYTES  = (size_t)B_ * HW_ * C_ * 2;      // 50,331,648
    const size_t WQ_BYTES  = 640 * C_ * 2;                   // 245,760 (padded)
    const size_t WF_BYTES  = (size_t)B_ * 256 * C_ * 2;      // 786,432 (padded)
    const size_t QKV_BYTES = (size_t)B_ * OC3 * HW_ * 2;     // 150,994,944

    size_t off = 0;
    __bf16* Xt    = (__bf16*)(ws + off); off += XT_BYTES;    // later reused as vt
    __bf16* Wq    = (__bf16*)(ws + off); off += WQ_BYTES;
    __bf16* Wf    = (__bf16*)(ws + off); off += WF_BYTES;
    bf16*   bufA  = (bf16*)(ws + off);   off += QKV_BYTES;   // qkv after 1x1
    bf16*   bufB  = (bf16*)(ws + off);   off += QKV_BYTES;   // qkv after dwconv
    float*  sumsq = (float*)(ws + off);  off += OC3 * B_ * 4;
    float*  Spart = (float*)(ws + off);  off += (size_t)32 * 2304 * 4 * 32; // 9.4 MB
    float*  Sred  = (float*)(ws + off);  off += (size_t)32 * 2304 * 4;      // 294 KB
    float*  Attn  = (float*)(ws + off);  off += 294912;
    __bf16* vt    = Xt;  // Xt dead after qkv GEMM

    cvt_w<<<dim3(OC3), 192, 0, stream>>>(qkv_w, Wq);

    tx_cvt<<<dim3(HW_ / 128, 1, B_), 256, 0, stream>>>(x, Xt);

    mfma_gemm<bf16, C_><<<dim3(HW_ / 256, 5, B_), 512, 0, stream>>>(
        Wq, Xt, qkv_b, bufA, OC3, 0);

    dwconv_fused<<<dim3(OC3, B_), 256, 0, stream>>>(bufA, dw_w, dw_b, bufB, sumsq);

    qk_mfma<<<dim3(32, HEADS_, B_), 256, 0, stream>>>(bufB, Spart);

    sreduce<<<dim3(9, 32), 256, 0, stream>>>(Spart, Sred);

    softmax48<<<dim3(HEADS_, B_), 64, 0, stream>>>(Sred, sumsq, temp, Attn);

    vtx<<<dim3(HW_ / 128, 1, B_), 256, 0, stream>>>(bufB, vt);

    wfuse<<<dim3(C_, B_), 192, 0, stream>>>(proj_w, Attn, Wf);

    mfma_gemm<float, C_><<<dim3(HW_ / 256, 2, B_), 512, 0, stream>>>(
        Wf, vt, proj_b, out, C_, (size_t)256 * C_);
}

// Round 7
// 395.525 us; speedup vs baseline: 1.0155x; 1.0155x over previous
//
#include <hip/hip_runtime.h>
#include <hip/hip_bf16.h>

typedef __hip_bfloat16 bf16;

#define B_   8
#define C_   192
#define OC3  576
#define H_   128
#define W_   128
#define HW_  16384
#define HEADS_ 4
#define D_   48

typedef float f32x4 __attribute__((ext_vector_type(4)));
typedef __bf16 bf16x8 __attribute__((ext_vector_type(8)));
typedef __bf16 bf16x4 __attribute__((ext_vector_type(4)));

__device__ __forceinline__ float b2f(bf16 v) { return __bfloat162float(v); }

// packed 4-wide epilogue stores (p-contiguous)
__device__ __forceinline__ void stv4(bf16* p, const f32x4& v, float bi) {
    bf16x4 o;
#pragma unroll
    for (int r = 0; r < 4; ++r) o[r] = (__bf16)(v[r] + bi);
    *reinterpret_cast<bf16x4*>(p) = o;
}
__device__ __forceinline__ void stv4(float* p, const f32x4& v, float bi) {
    f32x4 o;
#pragma unroll
    for (int r = 0; r < 4; ++r) o[r] = v[r] + bi;
    *reinterpret_cast<f32x4*>(p) = o;
}

// async 16B global -> LDS (per-lane global addr; LDS dest = wave-uniform base + lane*16)
__device__ __forceinline__ void llds16(const void* g, void* l) {
    __builtin_amdgcn_global_load_lds(
        (const __attribute__((address_space(1))) unsigned int*)g,
        (__attribute__((address_space(3))) unsigned int*)l, 16, 0, 0);
}

// ---------------------------------------------------------------------------
// Convert qkv_w (576x192) fp32 -> bf16 (rows padded to 640; pad rows = finite
// poison, masked at GEMM store). grid 576 x 192 threads.
// ---------------------------------------------------------------------------
__global__ void cvt_w(const float* __restrict__ qkv_w, __bf16* __restrict__ Wq) {
    const int row = blockIdx.x, c = threadIdx.x;
    Wq[row * C_ + c] = (__bf16)qkv_w[row * C_ + c];
}

// ---------------------------------------------------------------------------
// Transpose-convert x[b][c][p] fp32 -> Xt[b][p][c] bf16.
// ---------------------------------------------------------------------------
__global__ void tx_cvt(const float* __restrict__ x, __bf16* __restrict__ Xt) {
    const int p0 = blockIdx.x * 128;
    const int b  = blockIdx.z;
    __shared__ __bf16 LT[128 * 196];

    for (int idx = threadIdx.x; idx < C_ * 128; idx += 256) {
        int c = idx >> 7, pp = idx & 127;
        LT[pp * 196 + c] = (__bf16)x[((size_t)b * C_ + c) * HW_ + p0 + pp];
    }
    __syncthreads();
    for (int idx = threadIdx.x; idx < 128 * 48; idx += 256) {
        int pp = idx / 48, c4 = idx % 48;
        *(uint2*)&Xt[((size_t)b * HW_ + p0 + pp) * C_ + c4 * 4] =
            *(const uint2*)&LT[pp * 196 + c4 * 4];
    }
}

// ---------------------------------------------------------------------------
// Transpose v-part of qkv2: vt[b][p][c] (c=0..191 => channel 384+c) bf16.
// ---------------------------------------------------------------------------
__global__ void vtx(const bf16* __restrict__ qkv2, __bf16* __restrict__ vt) {
    const int p0 = blockIdx.x * 128;
    const int b  = blockIdx.z;
    const bf16* vb = qkv2 + ((size_t)b * OC3 + 384) * HW_;
    __shared__ __bf16 LT[128 * 200];

    for (int idx = threadIdx.x; idx < C_ * 128; idx += 256) {
        int c = idx >> 7, pp = idx & 127;
        LT[pp * 200 + c] = *(const __bf16*)&vb[(size_t)c * HW_ + p0 + pp];
    }
    __syncthreads();
    for (int idx = threadIdx.x; idx < 128 * 48; idx += 256) {
        int pp = idx / 48, c4 = idx % 48;
        *(uint2*)&vt[((size_t)b * HW_ + p0 + pp) * C_ + c4 * 4] =
            *(const uint2*)&LT[pp * 200 + c4 * 4];
    }
}

// ---------------------------------------------------------------------------
// MFMA GEMM (BT form): Y[b][o][p] = sum_k A[o][k] * Xt[b][p][k] + bias[o]
// A rows padded to grid_y*128; a_bstride selects per-batch A (0 = shared).
//
// v4 (measured best: 73.7 us qkv — v5's 2-deep+setprio regressed to 76.9,
//     occupancy-via-smaller-LDS theory refuted, reverted):
//     BM=128 x BN=256, 8 waves (512 thr), 3-deep LDS pipeline w/ counted
//     vmcnt(3) — tile t+1's 3 loads stay in flight across the barrier.
//     Both-sides XOR swizzle (slot = k8 ^ ((row>>1)&3)): staging is
//     64B-contiguous per row, ds_read starting banks 2-way max (free).
//     MFMA operands swapped (X as A operand) -> acc regs run along p ->
//     packed 8B/16B epilogue stores.
// ---------------------------------------------------------------------------
template<typename TOut, int KK>
__global__ __launch_bounds__(512, 4) void mfma_gemm(
        const __bf16* __restrict__ Wp, const __bf16* __restrict__ Xt,
        const float* __restrict__ bias, TOut* __restrict__ Y,
        const int O, const size_t a_bstride) {
    const int tid  = threadIdx.x;
    const int wid  = tid >> 6, lane = tid & 63;
    const int lm   = lane & 15, qd = lane >> 4;
    const int p0   = blockIdx.x * 256;
    const int o0   = blockIdx.y * 128;
    const int b    = blockIdx.z;
    const int wo0  = (wid >> 2) * 64;      // 2 o-rows of waves
    const int wn0  = (wid & 3) * 64;       // 4 p-cols of waves

    const __bf16* Wb = Wp + a_bstride * b + (size_t)o0 * KK;
    const __bf16* Xb = Xt + ((size_t)b * HW_ + p0) * KK;

    // [buf][row][slot][8] bf16 (lane-linear for global_load_lds); the 16B
    // chunk at (row,slot) holds global k8 = slot ^ ((row>>1)&3).
    __shared__ __bf16 As[3][4096];    // 128 rows x 32k  (8 KB/buf)
    __shared__ __bf16 Bs[3][8192];    // 256 rows x 32k  (16 KB/buf)

    f32x4 acc[4][4] = {};

    auto stage = [&](int buf, int t) {
        const int k0 = t * 32;
        {   // A: 128 rows x 4 chunks = 512 = 1/thread
            const int row = tid >> 2, cslot = tid & 3;
            const int k8  = cslot ^ ((row >> 1) & 3);
            llds16(Wb + (size_t)row * KK + k0 + k8 * 8,
                   &As[buf][(size_t)(wid * 64) * 8]);
        }
#pragma unroll
        for (int r = 0; r < 2; ++r) {   // B: 256 rows x 4 chunks = 1024 = 2/thread
            const int slot = r * 512 + tid;
            const int row  = slot >> 2, cslot = slot & 3;
            const int k8   = cslot ^ ((row >> 1) & 3);
            llds16(Xb + (size_t)row * KK + k0 + k8 * 8,
                   &Bs[buf][(size_t)(r * 512 + wid * 64) * 8]);
        }
    };

    constexpr int NT = KK >> 5;     // 6

    // pipeline fill: tiles 0 and 1 in flight (6 loads/thread)
    stage(0, 0);
    stage(1, 1);

    const int csl = qd ^ ((lm >> 1) & 3);  // swizzled chunk slot for ds_read

#pragma unroll
    for (int t = 0; t < NT; ++t) {
        __builtin_amdgcn_sched_barrier(0);
        // wait for tile t only; tile t+1's 3 loads stay outstanding
        if (t < NT - 1) asm volatile("s_waitcnt vmcnt(3)" ::: "memory");
        else            asm volatile("s_waitcnt vmcnt(0)" ::: "memory");
        __builtin_amdgcn_s_barrier();
        __builtin_amdgcn_sched_barrier(0);

        if (t + 2 < NT) stage((t + 2) % 3, t + 2);  // 2-ahead prefetch

        const int cur = t % 3;                       // static after unroll
        bf16x8 af[4], bfr[4];
#pragma unroll
        for (int i = 0; i < 4; ++i)
            af[i] = *(const bf16x8*)&As[cur][((wo0 + i * 16 + lm) * 4 + csl) * 8];
#pragma unroll
        for (int j = 0; j < 4; ++j)
            bfr[j] = *(const bf16x8*)&Bs[cur][((wn0 + j * 16 + lm) * 4 + csl) * 8];
#pragma unroll
        for (int i = 0; i < 4; ++i)
#pragma unroll
            for (int j = 0; j < 4; ++j)
                // swapped: X-frag is the A operand -> D reg index runs along p
                acc[i][j] = __builtin_amdgcn_mfma_f32_16x16x32_bf16(
                    bfr[j], af[i], acc[i][j], 0, 0, 0);
    }

    // epilogue: acc[i][j][r] = Y[o0+wo0+i*16+lm][p0+wn0+j*16+qd*4+r]
    TOut* Yb = Y + (size_t)b * O * HW_;
#pragma unroll
    for (int i = 0; i < 4; ++i) {
        const int o = o0 + wo0 + i * 16 + lm;
        if (o < O) {
            const float bi = bias[o];
#pragma unroll
            for (int j = 0; j < 4; ++j) {
                const int p = p0 + wn0 + j * 16 + qd * 4;
                stv4(&Yb[(size_t)o * HW_ + p], acc[i][j], bi);
            }
        }
    }
}

// ---------------------------------------------------------------------------
// depthwise 3x3 + fused sum-of-squares (for q,k L2 norms).
// grid (ch=576, b=8), block 256. Whole 128x128 plane staged in LDS (32 KB).
// v2: statically-rotated rows[3] window (full unroll -> constexpr indices;
//     removes ~160 v_mov/thread of shift-chain); sumsq reduction + its 8
//     barriers skipped for v channels (ch >= 384; sumsq only read for q,k).
// ---------------------------------------------------------------------------
__device__ __forceinline__ void dw_load_row(const __bf16* plane, int yy, int x0,
                                            float* r) {
    if (yy < 0 || yy > 127) {
#pragma unroll
        for (int i = 0; i < 10; ++i) r[i] = 0.f;
        return;
    }
    const __bf16* row = plane + yy * 128;
    bf16x8 v = *(const bf16x8*)(row + x0);
    r[0] = (x0 > 0) ? (float)row[x0 - 1] : 0.f;
#pragma unroll
    for (int i = 0; i < 8; ++i) r[1 + i] = (float)v[i];
    r[9] = (x0 + 8 < 128) ? (float)row[x0 + 8] : 0.f;
}

__global__ __launch_bounds__(256) void dwconv_fused(
        const bf16* __restrict__ in, const float* __restrict__ w9,
        const float* __restrict__ bias, bf16* __restrict__ out,
        float* __restrict__ sumsq) {
    const int ch = blockIdx.x;
    const int b  = blockIdx.y;
    const int tid = threadIdx.x;
    const char* ib = (const char*)(in + ((size_t)b * OC3 + ch) * HW_);

    __shared__ __bf16 plane[16384];
    __shared__ float red[256];

    {
        const int wid = tid >> 6, lane = tid & 63;
        char* lbase = (char*)plane + wid * 8192;
        const char* gbase = ib + wid * 8192;
#pragma unroll
        for (int i = 0; i < 8; ++i)
            llds16(gbase + i * 1024 + lane * 16, lbase + i * 1024);
    }

    float wv[9];
#pragma unroll
    for (int i = 0; i < 9; ++i) wv[i] = w9[ch * 9 + i];
    const float bi = bias[ch];

    __syncthreads();

    const int x0 = (tid & 15) * 8;
    const int y0 = (tid >> 4) * 8;
    bf16* ob = out + ((size_t)b * OC3 + ch) * HW_;

    float rows[3][10];
    dw_load_row(plane, y0 - 1, x0, rows[0]);
    dw_load_row(plane, y0,     x0, rows[1]);

    float ss = 0.f;
#pragma unroll
    for (int yi = 0; yi < 8; ++yi) {
        float* r0 = rows[yi % 3];            // constexpr after full unroll
        float* r1 = rows[(yi + 1) % 3];
        float* r2 = rows[(yi + 2) % 3];
        dw_load_row(plane, y0 + yi + 1, x0, r2);
        bf16x8 st;
#pragma unroll
        for (int xx = 0; xx < 8; ++xx) {
            float o = bi;
#pragma unroll
            for (int dx = 0; dx < 3; ++dx) {
                o += wv[0 + dx] * r0[xx + dx];
                o += wv[3 + dx] * r1[xx + dx];
                o += wv[6 + dx] * r2[xx + dx];
            }
            ss += o * o;
            st[xx] = (__bf16)o;
        }
        *(bf16x8*)(ob + (y0 + yi) * 128 + x0) = st;
    }

    if (ch < 384) {               // block-uniform: only q,k channels need norms
        red[tid] = ss;
        __syncthreads();
        for (int stx = 128; stx > 0; stx >>= 1) {
            if (tid < stx) red[tid] += red[tid + stx];
            __syncthreads();
        }
        if (tid == 0) sumsq[b * OC3 + ch] = red[0];
    }
}

// ---------------------------------------------------------------------------
// MFMA QK^T partials: S_part[slice][i][j] = sum_{n in 512-slice} q[i,n]*k[j,n]
// grid (32, HEADS, B), 256 thr. LDS: q/k chunks 48x128, rows padded to 136
// (row stride 17*16B => 2-way max bank aliasing on ds_read_b128). 4 waves
// split each 128-chunk into K=32 pieces; fp32 cross-wave reduce in LDS.
// ---------------------------------------------------------------------------
__global__ __launch_bounds__(256) void qk_mfma(const bf16* __restrict__ qkv2,
                                               float* __restrict__ Spart) {
    const int slice = blockIdx.x, h = blockIdx.y, b = blockIdx.z;
    const __bf16* qb = (const __bf16*)(qkv2 + ((size_t)b * OC3 + h * D_) * HW_);
    const __bf16* kb = (const __bf16*)(qkv2 + ((size_t)b * OC3 + 192 + h * D_) * HW_);

    __shared__ char smem[36864];                 // max(staging 26112, reduce 36864)
    __bf16* qs = (__bf16*)smem;                  // 48 x 136
    __bf16* ks = (__bf16*)(smem + 13056);        // 48 x 136
    float*  red = (float*)smem;                  // 4 x 2304

    const int tid = threadIdx.x, wid = tid >> 6, lane = tid & 63;
    const int lm = lane & 15, qd = lane >> 4;
    const int kw0 = wid * 32;

    f32x4 acc[3][3] = {};

    for (int sub = 0; sub < 4; ++sub) {
        const int n0 = slice * 512 + sub * 128;
        __syncthreads();
        for (int t = tid; t < 768; t += 256) {
            int r = t >> 4, c8 = t & 15;
            *(bf16x8*)&qs[r * 136 + c8 * 8] =
                *(const bf16x8*)(qb + (size_t)r * HW_ + n0 + c8 * 8);
            *(bf16x8*)&ks[r * 136 + c8 * 8] =
                *(const bf16x8*)(kb + (size_t)r * HW_ + n0 + c8 * 8);
        }
        __syncthreads();

        bf16x8 af[3], bfr[3];
#pragma unroll
        for (int i = 0; i < 3; ++i)
            af[i] = *(const bf16x8*)&qs[(i * 16 + lm) * 136 + kw0 + qd * 8];
#pragma unroll
        for (int j = 0; j < 3; ++j)
            bfr[j] = *(const bf16x8*)&ks[(j * 16 + lm) * 136 + kw0 + qd * 8];
#pragma unroll
        for (int i = 0; i < 3; ++i)
#pragma unroll
            for (int j = 0; j < 3; ++j)
                acc[i][j] = __builtin_amdgcn_mfma_f32_16x16x32_bf16(
                    af[i], bfr[j], acc[i][j], 0, 0, 0);
    }

    __syncthreads();
    float* wb = red + wid * 2304;
#pragma unroll
    for (int i = 0; i < 3; ++i)
#pragma unroll
        for (int j = 0; j < 3; ++j)
#pragma unroll
            for (int r = 0; r < 4; ++r)
                wb[(i * 16 + qd * 4 + r) * 48 + j * 16 + lm] = acc[i][j][r];
    __syncthreads();

    float* outp = Spart + ((size_t)((b * HEADS_ + h) * 32 + slice)) * 2304;
    for (int t = tid; t < 2304; t += 256)
        outp[t] = red[t] + red[2304 + t] + red[4608 + t] + red[6912 + t];
}

// ---------------------------------------------------------------------------
// Parallel 32-slice reduction: Sred[bh][t] = sum_sl Spart[bh][sl][t].
// grid (9, 32bh) x 256 thr = one thread per output element; coalesced loads.
// ---------------------------------------------------------------------------
__global__ void sreduce(const float* __restrict__ Spart, float* __restrict__ Sred) {
    const int bh = blockIdx.y;
    const int t  = blockIdx.x * 256 + threadIdx.x;   // 9*256 = 2304 exactly
    const float* Sp = Spart + (size_t)bh * 32 * 2304;
    float v = 0.f;
#pragma unroll
    for (int sl = 0; sl < 32; ++sl) v += Sp[sl * 2304 + t];
    Sred[(size_t)bh * 2304 + t] = v;
}

// ---------------------------------------------------------------------------
// apply norms (from fused sumsq) + temperature, softmax over pre-reduced S.
// ---------------------------------------------------------------------------
__global__ void softmax48(const float* __restrict__ Sred, const float* __restrict__ sumsq,
                          const float* __restrict__ temp, float* __restrict__ A) {
    const int h = blockIdx.x, b = blockIdx.y;
    const int i = threadIdx.x;
    if (i >= 48) return;
    const float* sq = sumsq + b * OC3 + h * D_;
    const float* sk = sumsq + b * OC3 + 192 + h * D_;
    const float t = temp[h];
    const float* Sp = Sred + (size_t)(b * HEADS_ + h) * 2304;

    const float rqi = 1.0f / fmaxf(sqrtf(sq[i]), 1e-12f);

    float s[48];
#pragma unroll
    for (int j = 0; j < 48; ++j)
        s[j] = Sp[i * 48 + j] * rqi * (1.0f / fmaxf(sqrtf(sk[j]), 1e-12f)) * t;
    float m = -1e30f;
#pragma unroll
    for (int j = 0; j < 48; ++j) m = fmaxf(m, s[j]);
    float sum = 0.f;
#pragma unroll
    for (int j = 0; j < 48; ++j) { s[j] = expf(s[j] - m); sum += s[j]; }
    float inv = 1.0f / sum;
    float* Ao = A + ((size_t)(b * HEADS_ + h) * 48 + i) * 48;
#pragma unroll
    for (int j = 0; j < 48; ++j) Ao[j] = s[j] * inv;
}

// ---------------------------------------------------------------------------
// Wf[b][o][c'] = sum_i proj_w[o][h*48+i] * A[b,h][i][j]   (c' = h*48+j)
// ---------------------------------------------------------------------------
__global__ void wfuse(const float* __restrict__ proj_w, const float* __restrict__ A,
                      __bf16* __restrict__ Wf) {
    const int o = blockIdx.x, b = blockIdx.y;
    const int cp = threadIdx.x;
    const int h = cp / 48, j = cp % 48;
    const float* wrow = proj_w + o * C_ + h * D_;
    const float* Ah = A + (size_t)(b * HEADS_ + h) * 2304;
    float s = 0.f;
#pragma unroll
    for (int i = 0; i < 48; ++i) s += wrow[i] * Ah[i * 48 + j];
    Wf[((size_t)b * 256 + o) * C_ + cp] = (__bf16)s;
}

// ---------------------------------------------------------------------------
extern "C" void kernel_launch(void* const* d_in, const int* in_sizes, int n_in,
                              void* d_out, int out_size, void* d_ws, size_t ws_size,
                              hipStream_t stream) {
    const float* x      = (const float*)d_in[0];
    const float* qkv_w  = (const float*)d_in[1];
    const float* qkv_b  = (const float*)d_in[2];
    const float* dw_w   = (const float*)d_in[3];
    const float* dw_b   = (const float*)d_in[4];
    const float* temp   = (const float*)d_in[5];
    const float* proj_w = (const float*)d_in[6];
    const float* proj_b = (const float*)d_in[7];
    float* out = (float*)d_out;

    char* ws = (char*)d_ws;
    const size_t XT_BYTES  = (size_t)B_ * HW_ * C_ * 2;      // 50,331,648
    const size_t WQ_BYTES  = 640 * C_ * 2;                   // 245,760 (padded)
    const size_t WF_BYTES  = (size_t)B_ * 256 * C_ * 2;      // 786,432 (padded)
    const size_t QKV_BYTES = (size_t)B_ * OC3 * HW_ * 2;     // 150,994,944

    size_t off = 0;
    __bf16* Xt    = (__bf16*)(ws + off); off += XT_BYTES;    // later reused as vt
    __bf16* Wq    = (__bf16*)(ws + off); off += WQ_BYTES;
    __bf16* Wf    = (__bf16*)(ws + off); off += WF_BYTES;
    bf16*   bufA  = (bf16*)(ws + off);   off += QKV_BYTES;   // qkv after 1x1
    bf16*   bufB  = (bf16*)(ws + off);   off += QKV_BYTES;   // qkv after dwconv
    float*  sumsq = (float*)(ws + off);  off += OC3 * B_ * 4;
    float*  Spart = (float*)(ws + off);  off += (size_t)32 * 2304 * 4 * 32; // 9.4 MB
    float*  Sred  = (float*)(ws + off);  off += (size_t)32 * 2304 * 4;      // 294 KB
    float*  Attn  = (float*)(ws + off);  off += 294912;
    __bf16* vt    = Xt;  // Xt dead after qkv GEMM

    cvt_w<<<dim3(OC3), 192, 0, stream>>>(qkv_w, Wq);

    tx_cvt<<<dim3(HW_ / 128, 1, B_), 256, 0, stream>>>(x, Xt);

    mfma_gemm<bf16, C_><<<dim3(HW_ / 256, 5, B_), 512, 0, stream>>>(
        Wq, Xt, qkv_b, bufA, OC3, 0);

    dwconv_fused<<<dim3(OC3, B_), 256, 0, stream>>>(bufA, dw_w, dw_b, bufB, sumsq);

    qk_mfma<<<dim3(32, HEADS_, B_), 256, 0, stream>>>(bufB, Spart);

    sreduce<<<dim3(9, 32), 256, 0, stream>>>(Spart, Sred);

    softmax48<<<dim3(HEADS_, B_), 64, 0, stream>>>(Sred, sumsq, temp, Attn);

    vtx<<<dim3(HW_ / 128, 1, B_), 256, 0, stream>>>(bufB, vt);

    wfuse<<<dim3(C_, B_), 192, 0, stream>>>(proj_w, Attn, Wf);

    mfma_gemm<float, C_><<<dim3(HW_ / 256, 2, B_), 512, 0, stream>>>(
        Wf, vt, proj_b, out, C_, (size_t)256 * C_);
}